// Round 4
// baseline (88.596 us; speedup 1.0000x reference)
//
#include <hip/hip_runtime.h>
#include <hip/hip_bf16.h>
#include <math.h>

typedef short bf16x8 __attribute__((ext_vector_type(8)));
typedef float f32x4 __attribute__((ext_vector_type(4)));
typedef unsigned short u16;

#define AS1(p) ((const __attribute__((address_space(1))) unsigned int*)(p))
#define AS3(p) ((__attribute__((address_space(3))) unsigned int*)(p))

#define WAITVM24 asm volatile("s_waitcnt vmcnt(24)" ::: "memory")
#define WAITVM0  asm volatile("s_waitcnt vmcnt(0)"  ::: "memory")
#define LGKM0    asm volatile("s_waitcnt lgkmcnt(0)" ::: "memory")

__device__ __forceinline__ u16 f2bf(float f) {
  union { float f; unsigned u; } v; v.f = f;
  unsigned r = v.u + 0x7fffu + ((v.u >> 16) & 1u);  // RNE
  return (u16)(r >> 16);
}

// pack 8 fp32 -> 8 bf16 by truncation (exact for 0.0/1.0 adj values)
__device__ __forceinline__ bf16x8 pack8_trunc(const f32x4& a, const f32x4& b) {
  union { f32x4 f; unsigned u[4]; } ua, ub; ua.f = a; ub.f = b;
  union { bf16x8 v; unsigned u[4]; } r;
  r.u[0] = (ua.u[0] >> 16) | (ua.u[1] & 0xFFFF0000u);
  r.u[1] = (ua.u[2] >> 16) | (ua.u[3] & 0xFFFF0000u);
  r.u[2] = (ub.u[0] >> 16) | (ub.u[1] & 0xFFFF0000u);
  r.u[3] = (ub.u[2] >> 16) | (ub.u[3] & 0xFFFF0000u);
  return r.v;
}

// ---------- Kernel 0: Wt[f][k] = bf16(W[k][f]) (256x256) ----------
__global__ void k_wt(const float* __restrict__ W, u16* __restrict__ Wt) {
  int idx = blockIdx.x * 256 + threadIdx.x;
#pragma unroll
  for (int q = 0; q < 4; ++q) {
    int i = idx + q * 16384;
    int f = i & 255, k = i >> 8;
    Wt[f * 256 + k] = f2bf(W[k * 256 + f]);
  }
}

// ---------- Kernel A: ht[b][f][j] = bf16( (x @ W)[b,j,f] ) ----------
__global__ __launch_bounds__(512, 4) void k_xw(
    const float* __restrict__ x, const u16* __restrict__ Wt, u16* __restrict__ ht)
{
  __shared__ u16 Ab[2][32 * 64];
  __shared__ u16 Bb[2][256 * 64];

  const int tid = threadIdx.x;
  const int lane = tid & 63;
  const int wid = tid >> 6;
  const int wr = wid >> 2, wc = wid & 3;

  const long row0 = (long)blockIdx.x * 32;
  const int b = (int)(row0 >> 11);
  const int jloc = (int)(row0 & 2047);
  const float* xb = x + row0 * 256;
  u16* htb = ht + ((size_t)b << 19);

  const int ar = tid >> 4;
  const int ac = tid & 15;
  const int awb = ar * 128 + ((ac * 8) ^ ((ar & 7) << 4));

  f32x4 acc[4] = {};

  auto stage = [&](int t, int bufi) {
    const float4 v = *(const float4*)(xb + ar * 256 + t * 64 + ac * 4);
    short4 p;
    p.x = (short)f2bf(v.x); p.y = (short)f2bf(v.y);
    p.z = (short)f2bf(v.z); p.w = (short)f2bf(v.w);
    *(short4*)((char*)(&Ab[bufi][0]) + awb) = p;
#pragma unroll
    for (int q = 0; q < 4; ++q) {
      const int fbase = wid * 32 + q * 8;
      const int f = fbase + (lane >> 3);
      const char* src = (const char*)Wt + f * 512 + t * 128
                        + (((lane & 7) * 16) ^ ((f & 7) << 4));
      __builtin_amdgcn_global_load_lds(AS1(src),
          AS3((char*)(&Bb[bufi][0]) + fbase * 128), 16, 0, 0);
    }
  };

  auto compute = [&](int bufi) {
#pragma unroll
    for (int kk = 0; kk < 2; ++kk) {
      const int am = wr * 16 + (lane & 15);
      const bf16x8 a = *(const bf16x8*)((const char*)(&Ab[bufi][0])
          + am * 128 + ((kk * 64 + (lane >> 4) * 16) ^ ((am & 7) << 4)));
#pragma unroll
      for (int nf = 0; nf < 4; ++nf) {
        const int bn = wc * 64 + nf * 16 + (lane & 15);
        const bf16x8 bv = *(const bf16x8*)((const char*)(&Bb[bufi][0])
            + bn * 128 + ((kk * 64 + (lane >> 4) * 16) ^ ((bn & 7) << 4)));
        acc[nf] = __builtin_amdgcn_mfma_f32_16x16x32_bf16(a, bv, acc[nf], 0, 0, 0);
      }
    }
  };

  stage(0, 0);
  __syncthreads();
#pragma unroll 2
  for (int t = 0; t < 4; ++t) {
    const int cur = t & 1;
    if (t + 1 < 4) stage(t + 1, cur ^ 1);
    compute(cur);
    __syncthreads();
  }

  const int j0 = jloc + wr * 16 + ((lane >> 4) << 2);
#pragma unroll
  for (int nf = 0; nf < 4; ++nf) {
    const int f = wc * 64 + nf * 16 + (lane & 15);
    short4 p;
    p.x = (short)f2bf(acc[nf][0]);
    p.y = (short)f2bf(acc[nf][1]);
    p.z = (short)f2bf(acc[nf][2]);
    p.w = (short)f2bf(acc[nf][3]);
    *(short4*)(&htb[(size_t)f * 2048 + j0]) = p;
  }
}

// ---------- Kernel B: out = elu( (1/deg) * adj @ h ) ----------
// BARRIER-FREE: 1 wave per block (64 thr). Wave owns 32 rows x 128 f.
// grid 1024 = 8 batches x 64 rowtiles x 2 f-halves (bid&7 = batch -> XCD-local ht).
// A (adj) staged as FP32 via global_load_lds (pre-swizzled src), packed to bf16
// at fragment-read time. B (ht bf16) staged via global_load_lds (pre-swizzled).
// deg computed by an extra MFMA against a constant all-ones B fragment (exact).
// Pipeline: depth-2 tiles, wave-local vmcnt(24); no s_barrier anywhere.
__global__ __launch_bounds__(64, 1) void k_agg(
    const float* __restrict__ adj, const u16* __restrict__ ht, float* __restrict__ out)
{
  __shared__ float Afs[2][32 * 64];   // adj tile [32 rows][64 k] fp32, swizzled
  __shared__ u16   Bb[2][128 * 64];   // ht tile  [128 f][64 k] bf16, swizzled

  const int lane = threadIdx.x;       // 0..63
  const int bid = blockIdx.x;
  const int b  = bid & 7;
  const int rt = (bid >> 3) & 63;
  const int ft = bid >> 9;            // 0 or 1

  const char* adjB = (const char*)adj + (((size_t)b * 2048 + rt * 32) * 2048) * 4;
  const char* htB  = (const char*)ht + (((size_t)b * 524288) + (size_t)ft * 262144) * 2;
  float* outb = out + ((size_t)b * 2048 + rt * 32) * 256 + ft * 128;

  // stage tile t into buf: 8 A-gloads (fp32) + 16 B-gloads = 24 VMEM / wave.
  // LDS dest is linear (base+lane*16); source carries the inverse swizzle.
  auto stage = [&](int t, int buf) {
#pragma unroll
    for (int q = 0; q < 8; ++q) {                       // A: rows q*4+(lane>>4)
      const int row = q * 4 + (lane >> 4);
      const int s16 = lane & 15;
      const char* src = adjB + (size_t)row * 8192 + (size_t)t * 256
                        + ((s16 ^ (row & 15)) * 16);
      __builtin_amdgcn_global_load_lds(AS1(src),
          AS3((char*)(&Afs[buf][0]) + q * 1024), 16, 0, 0);
    }
#pragma unroll
    for (int q = 0; q < 16; ++q) {                      // B: f = q*8+(lane>>3)
      const int f = q * 8 + (lane >> 3);
      const int s = lane & 7;
      const char* src = htB + (size_t)f * 4096 + (size_t)t * 128
                        + ((s ^ (f & 7)) * 16);
      __builtin_amdgcn_global_load_lds(AS1(src),
          AS3((char*)(&Bb[buf][0]) + q * 1024), 16, 0, 0);
    }
  };

  f32x4 acc[2][8] = {};
  f32x4 dacc[2] = {};
  bf16x8 vones;
#pragma unroll
  for (int i = 0; i < 8; ++i) vones[i] = (short)0x3F80;  // bf16 1.0

  const int g = lane >> 4;            // k-group 0..3
  const int c = lane & 15;            // row/col within fragment

  stage(0, 0);
  stage(1, 1);

  for (int t = 0; t < 32; ++t) {
    if (t < 31) { WAITVM24; } else { WAITVM0; }   // tile t landed; t+1 in flight
    const int buf = t & 1;
    const char* Abase = (const char*)(&Afs[buf][0]);
    const char* Bbase = (const char*)(&Bb[buf][0]);
#pragma unroll
    for (int kk = 0; kk < 2; ++kk) {
      bf16x8 af[2];
#pragma unroll
      for (int mf = 0; mf < 2; ++mf) {
        const int row = mf * 16 + c;
        const char* rb = Abase + row * 256;
        const f32x4 a0 = *(const f32x4*)(rb + (((kk * 8 + g * 2 + 0) ^ c) * 16));
        const f32x4 a1 = *(const f32x4*)(rb + (((kk * 8 + g * 2 + 1) ^ c) * 16));
        af[mf] = pack8_trunc(a0, a1);
        dacc[mf] = __builtin_amdgcn_mfma_f32_16x16x32_bf16(af[mf], vones, dacc[mf], 0, 0, 0);
      }
#pragma unroll
      for (int nf = 0; nf < 8; ++nf) {
        const int f = nf * 16 + c;
        const bf16x8 bv = *(const bf16x8*)(Bbase + f * 128
            + (((kk * 4 + g) ^ (f & 7)) * 16));
        acc[0][nf] = __builtin_amdgcn_mfma_f32_16x16x32_bf16(af[0], bv, acc[0][nf], 0, 0, 0);
        acc[1][nf] = __builtin_amdgcn_mfma_f32_16x16x32_bf16(af[1], bv, acc[1][nf], 0, 0, 0);
      }
    }
    LGKM0;                             // all LDS reads retired before overwrite
    if (t < 30) stage(t + 2, buf);     // refill same buf; gated by vmcnt at t+2
  }

  // epilogue: C row = mf*16 + g*4 + r, col = c; deg = dacc[mf][r] (every lane
  // holds its own rows' deg — ones-column makes all cols identical).
#pragma unroll
  for (int mf = 0; mf < 2; ++mf) {
#pragma unroll
    for (int r = 0; r < 4; ++r) {
      const float d = dacc[mf][r];
      const float sc = d > 0.f ? 1.f / d : (1.f / 2048.f);
      const size_t ro = (size_t)(mf * 16 + g * 4 + r) * 256;
#pragma unroll
      for (int nf = 0; nf < 8; ++nf) {
        const float v = acc[mf][nf][r] * sc;
        outb[ro + nf * 16 + c] = v > 0.f ? v : expm1f(v);
      }
    }
  }
}

extern "C" void kernel_launch(void* const* d_in, const int* in_sizes, int n_in,
                              void* d_out, int out_size, void* d_ws, size_t ws_size,
                              hipStream_t stream) {
  const float* x   = (const float*)d_in[0];
  const float* adj = (const float*)d_in[1];
  const float* W   = (const float*)d_in[2];
  // d_in[3] ('a') is mathematically dead: softmax rows are constant over the
  // active (adj>0) entries, so attention = 1/deg regardless of e.
  float* out = (float*)d_out;

  u16* Wt = (u16*)d_ws;                          // 256*256*2   = 128 KB
  u16* ht = (u16*)((char*)d_ws + (131072));      // 8*256*2048*2 = 8 MB

  k_wt<<<64, 256, 0, stream>>>(W, Wt);
  k_xw<<<512, 512, 0, stream>>>(x, Wt, ht);
  k_agg<<<1024, 64, 0, stream>>>(adj, ht, out);
}

// Round 5
// 70.217 us; speedup vs baseline: 1.2618x; 1.2618x over previous
//
#include <hip/hip_runtime.h>
#include <hip/hip_bf16.h>
#include <math.h>

typedef short bf16x8 __attribute__((ext_vector_type(8)));
typedef float f32x4 __attribute__((ext_vector_type(4)));
typedef unsigned short u16;

#define AS1(p) ((const __attribute__((address_space(1))) unsigned int*)(p))
#define AS3(p) ((__attribute__((address_space(3))) unsigned int*)(p))

#define WAITVM6 asm volatile("s_waitcnt vmcnt(6)" ::: "memory")
#define WAITVM0 asm volatile("s_waitcnt vmcnt(0)" ::: "memory")
#define BARRIER asm volatile("s_barrier" ::: "memory")

__device__ __forceinline__ u16 f2bf(float f) {
  union { float f; unsigned u; } v; v.f = f;
  unsigned r = v.u + 0x7fffu + ((v.u >> 16) & 1u);  // RNE
  return (u16)(r >> 16);
}

// pack 8 fp32 -> 8 bf16 by truncation (exact for 0.0/1.0 adj values)
__device__ __forceinline__ bf16x8 pack8_trunc(const f32x4& a, const f32x4& b) {
  union { f32x4 f; unsigned u[4]; } ua, ub; ua.f = a; ub.f = b;
  union { bf16x8 v; unsigned u[4]; } r;
  r.u[0] = (ua.u[0] >> 16) | (ua.u[1] & 0xFFFF0000u);
  r.u[1] = (ua.u[2] >> 16) | (ua.u[3] & 0xFFFF0000u);
  r.u[2] = (ub.u[0] >> 16) | (ub.u[1] & 0xFFFF0000u);
  r.u[3] = (ub.u[2] >> 16) | (ub.u[3] & 0xFFFF0000u);
  return r.v;
}

// ---------- Kernel 0: Wt[f][k] = bf16(W[k][f]) (256x256) ----------
__global__ void k_wt(const float* __restrict__ W, u16* __restrict__ Wt) {
  int idx = blockIdx.x * 256 + threadIdx.x;
#pragma unroll
  for (int q = 0; q < 4; ++q) {
    int i = idx + q * 16384;
    int f = i & 255, k = i >> 8;
    Wt[f * 256 + k] = f2bf(W[k * 256 + f]);
  }
}

// ---------- Kernel A: ht[b][f][j] = bf16( (x @ W)[b,j,f] ) ----------
__global__ __launch_bounds__(512, 4) void k_xw(
    const float* __restrict__ x, const u16* __restrict__ Wt, u16* __restrict__ ht)
{
  __shared__ u16 Ab[2][32 * 64];
  __shared__ u16 Bb[2][256 * 64];

  const int tid = threadIdx.x;
  const int lane = tid & 63;
  const int wid = tid >> 6;
  const int wr = wid >> 2, wc = wid & 3;

  const long row0 = (long)blockIdx.x * 32;
  const int b = (int)(row0 >> 11);
  const int jloc = (int)(row0 & 2047);
  const float* xb = x + row0 * 256;
  u16* htb = ht + ((size_t)b << 19);

  const int ar = tid >> 4;
  const int ac = tid & 15;
  const int awb = ar * 128 + ((ac * 8) ^ ((ar & 7) << 4));

  f32x4 acc[4] = {};

  auto stage = [&](int t, int bufi) {
    const float4 v = *(const float4*)(xb + ar * 256 + t * 64 + ac * 4);
    short4 p;
    p.x = (short)f2bf(v.x); p.y = (short)f2bf(v.y);
    p.z = (short)f2bf(v.z); p.w = (short)f2bf(v.w);
    *(short4*)((char*)(&Ab[bufi][0]) + awb) = p;
#pragma unroll
    for (int q = 0; q < 4; ++q) {
      const int fbase = wid * 32 + q * 8;
      const int f = fbase + (lane >> 3);
      const char* src = (const char*)Wt + f * 512 + t * 128
                        + (((lane & 7) * 16) ^ ((f & 7) << 4));
      __builtin_amdgcn_global_load_lds(AS1(src),
          AS3((char*)(&Bb[bufi][0]) + fbase * 128), 16, 0, 0);
    }
  };

  auto compute = [&](int bufi) {
#pragma unroll
    for (int kk = 0; kk < 2; ++kk) {
      const int am = wr * 16 + (lane & 15);
      const bf16x8 a = *(const bf16x8*)((const char*)(&Ab[bufi][0])
          + am * 128 + ((kk * 64 + (lane >> 4) * 16) ^ ((am & 7) << 4)));
#pragma unroll
      for (int nf = 0; nf < 4; ++nf) {
        const int bn = wc * 64 + nf * 16 + (lane & 15);
        const bf16x8 bv = *(const bf16x8*)((const char*)(&Bb[bufi][0])
            + bn * 128 + ((kk * 64 + (lane >> 4) * 16) ^ ((bn & 7) << 4)));
        acc[nf] = __builtin_amdgcn_mfma_f32_16x16x32_bf16(a, bv, acc[nf], 0, 0, 0);
      }
    }
  };

  stage(0, 0);
  __syncthreads();
#pragma unroll 2
  for (int t = 0; t < 4; ++t) {
    const int cur = t & 1;
    if (t + 1 < 4) stage(t + 1, cur ^ 1);
    compute(cur);
    __syncthreads();
  }

  const int j0 = jloc + wr * 16 + ((lane >> 4) << 2);
#pragma unroll
  for (int nf = 0; nf < 4; ++nf) {
    const int f = wc * 64 + nf * 16 + (lane & 15);
    short4 p;
    p.x = (short)f2bf(acc[nf][0]);
    p.y = (short)f2bf(acc[nf][1]);
    p.z = (short)f2bf(acc[nf][2]);
    p.w = (short)f2bf(acc[nf][3]);
    *(short4*)(&htb[(size_t)f * 2048 + j0]) = p;
  }
}

// ---------- Kernel B: out = elu( (1/deg) * adj @ h ) ----------
// 256 blocks (1/CU) = 8 batches x 32 rowtiles. Block tile 64m x 256n, BK=64.
// 8 waves = 4wr x 2wc; wave = 16m x 128n. Triple-ring LDS (A fp32 + B bf16),
// ONE barrier + counted vmcnt(6) per iter; stage(t+2) lands in the ring slot
// freed at t-1. adj read exactly once. deg via ones-MFMA (exact, lane-local).
__global__ __launch_bounds__(512, 1) void k_agg(
    const float* __restrict__ adj, const u16* __restrict__ ht, float* __restrict__ out)
{
  __shared__ float Abuf[3][64 * 64];   // 16KB x3: adj [64r][64k] fp32, slot^row
  __shared__ u16   Bbuf[3][256 * 64];  // 32KB x3: ht  [256f][64k] bf16, slot^f

  const int tid  = threadIdx.x;
  const int lane = tid & 63;
  const int wid  = tid >> 6;
  const int wr   = wid >> 1;          // 0..3: m-strip
  const int wc   = wid & 1;           // 0..1: f-half

  const int b  = blockIdx.x & 7;      // batch -> XCD-local ht
  const int rt = blockIdx.x >> 3;     // 0..31

  const char* adjB = (const char*)(adj + ((size_t)b * 2048 + rt * 64) * 2048);
  const char* htB  = (const char*)(ht + ((size_t)b << 19));
  float* outb = out + ((size_t)b * 2048 + rt * 64) * 256;

  // 6 VMEM/thread per stage: 4 B-gload_lds then 2 A-gload_lds (fixed order)
  auto stage = [&](int t, int r) {
#pragma unroll
    for (int q = 0; q < 4; ++q) {     // B: f = q*64 + wid*8 + (lane>>3)
      const int f = q * 64 + wid * 8 + (lane >> 3);
      const int s = lane & 7;
      const char* src = htB + (size_t)f * 4096 + (size_t)t * 128 + ((s ^ (f & 7)) * 16);
      __builtin_amdgcn_global_load_lds(AS1(src),
          AS3((char*)(&Bbuf[r][0]) + q * 8192 + wid * 1024), 16, 0, 0);
    }
#pragma unroll
    for (int q = 0; q < 2; ++q) {     // A: row = q*32 + wid*4 + (lane>>4)
      const int row = q * 32 + wid * 4 + (lane >> 4);
      const int s = lane & 15;
      const char* src = adjB + (size_t)row * 8192 + (size_t)t * 256 + ((s ^ (row & 15)) * 16);
      __builtin_amdgcn_global_load_lds(AS1(src),
          AS3((char*)(&Abuf[r][0]) + q * 8192 + wid * 1024), 16, 0, 0);
    }
  };

  f32x4 acc[8] = {};
  f32x4 dacc = {};
  bf16x8 vones;
#pragma unroll
  for (int i = 0; i < 8; ++i) vones[i] = (short)0x3F80;  // bf16 1.0

  const int g = lane >> 4;            // k-group 0..3
  const int c = lane & 15;            // frag row/col
  const int R = wr * 16 + c;          // A-tile row this lane reads

  stage(0, 0);
  stage(1, 1);

  for (int t = 0; t < 32; ++t) {
    if (t < 31) { WAITVM6; } else { WAITVM0; }   // tile t landed; t+1 in flight
    BARRIER;                                      // all waves' tile-t parts visible
    const int r = t % 3;
    if (t < 30) stage(t + 2, (t + 2) % 3);        // slot (t+2)%3==(t-1)%3: freed
    const char* Ab = (const char*)(&Abuf[r][0]);
    const char* Bb = (const char*)(&Bbuf[r][0]);
#pragma unroll
    for (int kk = 0; kk < 2; ++kk) {
      const f32x4 a0 = *(const f32x4*)(Ab + R * 256 + (((kk * 8 + g * 2 + 0) ^ (R & 15)) * 16));
      const f32x4 a1 = *(const f32x4*)(Ab + R * 256 + (((kk * 8 + g * 2 + 1) ^ (R & 15)) * 16));
      const bf16x8 af = pack8_trunc(a0, a1);
      dacc = __builtin_amdgcn_mfma_f32_16x16x32_bf16(af, vones, dacc, 0, 0, 0);
#pragma unroll
      for (int nf = 0; nf < 8; ++nf) {
        const int f = wc * 128 + nf * 16 + c;
        const bf16x8 bv = *(const bf16x8*)(Bb + f * 128 + (((kk * 4 + g) ^ (f & 7)) * 16));
        acc[nf] = __builtin_amdgcn_mfma_f32_16x16x32_bf16(af, bv, acc[nf], 0, 0, 0);
      }
    }
  }

  // epilogue: C row = g*4 + rr (within wave strip), col = c; deg = dacc[rr]
#pragma unroll
  for (int rr = 0; rr < 4; ++rr) {
    const float d = dacc[rr];
    const float sc = d > 0.f ? 1.f / d : (1.f / 2048.f);
    const size_t ro = (size_t)(wr * 16 + g * 4 + rr) * 256 + wc * 128;
#pragma unroll
    for (int nf = 0; nf < 8; ++nf) {
      const float v = acc[nf][rr] * sc;
      outb[ro + nf * 16 + c] = v > 0.f ? v : expm1f(v);
    }
  }
}

extern "C" void kernel_launch(void* const* d_in, const int* in_sizes, int n_in,
                              void* d_out, int out_size, void* d_ws, size_t ws_size,
                              hipStream_t stream) {
  const float* x   = (const float*)d_in[0];
  const float* adj = (const float*)d_in[1];
  const float* W   = (const float*)d_in[2];
  // d_in[3] ('a') is mathematically dead: softmax rows are constant over the
  // active (adj>0) entries, so attention = 1/deg regardless of e.
  float* out = (float*)d_out;

  u16* Wt = (u16*)d_ws;                          // 256*256*2   = 128 KB
  u16* ht = (u16*)((char*)d_ws + (131072));      // 8*256*2048*2 = 8 MB

  k_wt<<<64, 256, 0, stream>>>(W, Wt);
  k_xw<<<512, 512, 0, stream>>>(x, Wt, ht);
  k_agg<<<256, 512, 0, stream>>>(adj, ht, out);
}